// Round 6
// baseline (211.611 us; speedup 1.0000x reference)
//
#include <hip/hip_runtime.h>
#include <math.h>

// Problem constants
#define C_TOTAL 3072
#define C4 2048      // channels from l4 (upsampled half of concat: channels [0,2048))
#define C3 1024      // channels from l3 (channels [2048,3072))
#define HW  784      // 28*28
#define W_  28
#define HW4 196      // 14*14
#define W4  14
#define L_TOT 9      // landmarks + 1
#define NB  16       // batch
#define NK  2000     // classes
#define J3  16       // l3 channel chunks (64 ch each)

// Bilinear upsample 14->28, align_corners=False (jax.image.resize semantics):
// src = 0.5*o - 0.25; even o=2j: taps (j-1, j) w (0.25, 0.75); odd o=2j+1: taps (j, j+1) w (0.75, 0.25); clamp.
__device__ __forceinline__ void up_taps(int o, int& i0, int& i1, float& w0, float& w1) {
    int j = o >> 1;
    if (o & 1) { i0 = j;                       i1 = (j + 1 < W4) ? j + 1 : W4 - 1; w0 = 0.75f; w1 = 0.25f; }
    else       { i0 = (j - 1 > 0) ? j - 1 : 0; i1 = j;                             w0 = 0.25f; w1 = 0.75f; }
}

// weight that source index s contributes to output index o (adjoint of the upsample)
__device__ __forceinline__ float wdown(int o, int s) {
    int i0, i1; float w0, w1;
    up_taps(o, i0, i1, w0, w1);
    return (i0 == s ? w0 : 0.f) + (i1 == s ? w1 : 0.f);
}

// ------------- K1: fused front section — block-specialized on blockIdx.x ----------------------------
// x in [0,16):   ab4 chunk -> atomicAdd into ab4sum[b][l][q]   (q on 14x14 grid)
// x in [16,32):  ab3 chunk -> atomicAdd into absum[b][l][p]    (p on 28x28 grid)
// x == 32, b==0: asq[l] = sum_c Wl[l][c]^2 (plain store)
// absum/ab4sum are zeroed by hipMemsetAsync before this kernel.
__global__ __launch_bounds__(256) void abx_kernel(
    const float* __restrict__ l3, const float* __restrict__ l4,
    const float* __restrict__ Wl,
    float* __restrict__ ab4sum, float* __restrict__ absum, float* __restrict__ asqp)
{
    const int bx = blockIdx.x;
    const int b  = blockIdx.y;
    const int tid = threadIdx.x;

    if (bx < 16) {
        // ---- ab4 section ----
        const int q = tid;
        if (q >= HW4) return;
        const float* l4b = l4 + (size_t)b * C4 * HW4;
        float acc[L_TOT];
        #pragma unroll
        for (int l = 0; l < L_TOT; ++l) acc[l] = 0.f;
        const int c0 = bx * 128;
        #pragma unroll 8
        for (int i = 0; i < 128; ++i) {
            const int c = c0 + i;                       // wave-uniform -> scalar weight loads
            float xv = l4b[(size_t)c * HW4 + q];        // coalesced over q
            const float* wc = Wl + c;
            #pragma unroll
            for (int l = 0; l < L_TOT; ++l) acc[l] = fmaf(wc[l * C_TOTAL], xv, acc[l]);
        }
        float* outp = ab4sum + (size_t)b * (L_TOT * HW4) + q;
        #pragma unroll
        for (int l = 0; l < L_TOT; ++l) atomicAdd(&outp[l * HW4], acc[l]);
    } else if (bx < 32) {
        // ---- ab3 section ----
        const int t = tid;                  // float4 pixel group 0..195
        const int j = bx - 16;              // channel chunk
        if (t >= HW / 4) return;
        const float4* l3b = (const float4*)(l3 + (size_t)b * C3 * HW);
        float4 acc[L_TOT];
        #pragma unroll
        for (int l = 0; l < L_TOT; ++l) acc[l] = make_float4(0.f, 0.f, 0.f, 0.f);
        const int c0 = j * (C3 / J3);
        #pragma unroll 8
        for (int i = 0; i < C3 / J3; ++i) {
            const int c = c0 + i;                               // wave-uniform
            float4 xv = l3b[(size_t)c * (HW / 4) + t];          // 1 KB per wave instr
            const float* wc = Wl + C4 + c;
            #pragma unroll
            for (int l = 0; l < L_TOT; ++l) {
                const float w = wc[l * C_TOTAL];                // scalar load
                acc[l].x = fmaf(w, xv.x, acc[l].x);
                acc[l].y = fmaf(w, xv.y, acc[l].y);
                acc[l].z = fmaf(w, xv.z, acc[l].z);
                acc[l].w = fmaf(w, xv.w, acc[l].w);
            }
        }
        float* outp = absum + (size_t)b * (L_TOT * HW) + t * 4;
        #pragma unroll
        for (int l = 0; l < L_TOT; ++l) {
            float* o = outp + l * HW;
            atomicAdd(&o[0], acc[l].x);
            atomicAdd(&o[1], acc[l].y);
            atomicAdd(&o[2], acc[l].z);
            atomicAdd(&o[3], acc[l].w);
        }
    } else {
        // ---- asq section (one block total) ----
        if (b != 0) return;
        __shared__ float red[4];
        for (int l = 0; l < L_TOT; ++l) {
            const float* wrow = Wl + (size_t)l * C_TOTAL;
            float s0 = 0.f, s1 = 0.f, s2 = 0.f, s3 = 0.f;
            {
                float a = wrow[tid +  0 * 256];
                float bb = wrow[tid + 1 * 256];
                float c = wrow[tid +  2 * 256];
                float d = wrow[tid +  3 * 256];
                float e = wrow[tid +  4 * 256];
                float f = wrow[tid +  5 * 256];
                float gg = wrow[tid + 6 * 256];
                float h = wrow[tid +  7 * 256];
                float i2 = wrow[tid + 8 * 256];
                float j2 = wrow[tid + 9 * 256];
                float k2 = wrow[tid + 10 * 256];
                float m2 = wrow[tid + 11 * 256];
                s0 = fmaf(a, a, fmaf(e, e, i2 * i2));
                s1 = fmaf(bb, bb, fmaf(f, f, j2 * j2));
                s2 = fmaf(c, c, fmaf(gg, gg, k2 * k2));
                s3 = fmaf(d, d, fmaf(h, h, m2 * m2));
            }
            float s = (s0 + s1) + (s2 + s3);
            #pragma unroll
            for (int off = 32; off; off >>= 1) s += __shfl_down(s, off, 64);
            const int w = tid >> 6, lane = tid & 63;
            if (lane == 0) red[w] = s;
            __syncthreads();
            if (tid == 0) asqp[l] = (red[0] + red[1]) + (red[2] + red[3]);
            __syncthreads();
        }
    }
}

// ------------- K2: finalize — absum + upsample(ab4sum) + softmax -> maps ----------------------------
// Thread = output pixel. Grid (4 pixel chunks of 256, 16 b).
__global__ __launch_bounds__(256) void maps_fin_kernel(
    const float* __restrict__ absum, const float* __restrict__ ab4sum,
    const float* __restrict__ asqp, float* __restrict__ maps_out)
{
    __shared__ float ab4s[L_TOT * HW4];
    __shared__ float asq_s[L_TOT];

    const int tid = threadIdx.x;
    const int b   = blockIdx.y;
    const int p   = blockIdx.x * 256 + tid;

    for (int v = tid; v < L_TOT * HW4; v += 256)
        ab4s[v] = ab4sum[(size_t)b * (L_TOT * HW4) + v];
    if (tid < L_TOT) asq_s[tid] = asqp[tid];
    __syncthreads();
    if (p >= HW) return;

    const int y = p / W_, x = p % W_;
    int y0, y1, x0, x1; float wy0, wy1, wx0, wx1;
    up_taps(y, y0, y1, wy0, wy1);
    up_taps(x, x0, x1, wx0, wx1);

    const float* ap = absum + (size_t)b * (L_TOT * HW) + p;
    float lg[L_TOT];
    #pragma unroll
    for (int l = 0; l < L_TOT; ++l) {
        float s = ap[l * HW];                                   // coalesced over p
        const float* a = ab4s + l * HW4;
        float t0 = fmaf(a[y0 * W4 + x1], wx1, a[y0 * W4 + x0] * wx0);
        float t1 = fmaf(a[y1 * W4 + x1], wx1, a[y1 * W4 + x0] * wx0);
        float up = fmaf(t1, wy1, t0 * wy0);
        lg[l] = 2.f * (s + up) - asq_s[l];
    }
    float m = lg[0];
    #pragma unroll
    for (int l = 1; l < L_TOT; ++l) m = fmaxf(m, lg[l]);
    float sum = 0.f;
    #pragma unroll
    for (int l = 0; l < L_TOT; ++l) { lg[l] = __expf(lg[l] - m); sum += lg[l]; }
    const float inv = 1.f / sum;
    float* mp = maps_out + (size_t)b * L_TOT * HW + p;
    #pragma unroll
    for (int l = 0; l < L_TOT; ++l) mp[l * HW] = lg[l] * inv;
}

// ------------- K2b: maps_down[b][l][q] = downsample-adjoint of maps (once per b) --------------------
__global__ __launch_bounds__(256) void mapsdown_kernel(
    const float* __restrict__ maps, float* __restrict__ mdown)
{
    const int b   = blockIdx.x;
    const int tid = threadIdx.x;
    const float* mb = maps + (size_t)b * L_TOT * HW;
    for (int v = tid; v < L_TOT * HW4; v += 256) {
        const int l = v / HW4, q = v % HW4;
        const int sy = q / W4, sx = q % W4;
        float s = 0.f;
        int oy0 = 2 * sy - 1; if (oy0 < 0) oy0 = 0;
        int oy1 = 2 * sy + 2; if (oy1 > 27) oy1 = 27;
        int ox0 = 2 * sx - 1; if (ox0 < 0) ox0 = 0;
        int ox1 = 2 * sx + 2; if (ox1 > 27) ox1 = 27;
        for (int oy = oy0; oy <= oy1; ++oy) {
            const float wy = wdown(oy, sy);
            const float* row = mb + l * HW + oy * W_;
            for (int ox = ox0; ox <= ox1; ++ox)
                s = fmaf(wy * wdown(ox, sx), row[ox], s);
        }
        mdown[(size_t)b * (L_TOT * HW4) + v] = s;
    }
}

// ------------- K3: pooling -> all_features + g ------------------------------------------------------
// Block 256 = 4 waves x (4 ch-subgroups x 16 px-lanes); each lane owns 4 consecutive channels.
// l4 blocks (cblk<32): float4-load precomputed maps_down (7KB); read l4 directly (no upsample).
// l3 blocks: stage maps[9][784] into LDS. Block owns full pixel range -> no atomics.
__global__ __launch_bounds__(256) void pool_kernel(
    const float* __restrict__ l3, const float* __restrict__ l4,
    const float* __restrict__ maps, const float* __restrict__ mdown,
    const float* __restrict__ modulation,
    float* __restrict__ af_out, float* __restrict__ g_out)
{
    __shared__ float msh[L_TOT * HW];   // 28224 B; l4 blocks use first 9*196

    const int tid  = threadIdx.x;
    const int b    = blockIdx.y;
    const int cblk = blockIdx.x;        // 0..47
    const bool isl4 = (cblk < 32);

    if (isl4) {
        const float4* src = (const float4*)(mdown + (size_t)b * (L_TOT * HW4));
        for (int v = tid; v < (L_TOT * HW4) / 4; v += 256)   // 441 float4s
            ((float4*)msh)[v] = src[v];
    } else {
        const float4* src = (const float4*)(maps + (size_t)b * L_TOT * HW);
        for (int v = tid; v < (L_TOT * HW) / 4; v += 256)
            ((float4*)msh)[v] = src[v];
    }
    __syncthreads();

    const int   PMAX  = isl4 ? HW4 : HW;
    const float* xbase = isl4 ? (l4 + (size_t)b * C4 * HW4)
                              : (l3 + (size_t)b * C3 * HW);
    const int cloc0 = (isl4 ? cblk : (cblk - 32)) * 64;
    const int w = tid >> 6, s = (tid >> 4) & 3, t = tid & 15;
    const int cl = cloc0 + w * 16 + s * 4;      // local channel base of this lane's 4 channels

    float acc[4][L_TOT];
    #pragma unroll
    for (int j = 0; j < 4; ++j)
        #pragma unroll
        for (int l = 0; l < L_TOT; ++l) acc[j][l] = 0.f;

    const int kmax = isl4 ? 4 : 13;
    for (int k = 0; k < kmax; ++k) {
        const int p = (t << 2) + (k << 6);
        if (p < PMAX) {
            float4 m4[L_TOT];
            #pragma unroll
            for (int l = 0; l < L_TOT; ++l) m4[l] = *(const float4*)&msh[l * PMAX + p];
            #pragma unroll
            for (int j = 0; j < 4; ++j) {
                float4 x4 = *(const float4*)&xbase[(size_t)(cl + j) * PMAX + p];
                #pragma unroll
                for (int l = 0; l < L_TOT; ++l)
                    acc[j][l] = fmaf(x4.x, m4[l].x, fmaf(x4.y, m4[l].y,
                                fmaf(x4.z, m4[l].z, fmaf(x4.w, m4[l].w, acc[j][l]))));
            }
        }
    }

    // reduce across the 16 pixel-lanes of each subgroup
    #pragma unroll
    for (int j = 0; j < 4; ++j)
        #pragma unroll
        for (int l = 0; l < L_TOT; ++l) {
            float v = acc[j][l];
            v += __shfl_xor(v, 1, 16);
            v += __shfl_xor(v, 2, 16);
            v += __shfl_xor(v, 4, 16);
            v += __shfl_xor(v, 8, 16);
            acc[j][l] = v;
        }

    if (t == 0) {
        const float inv_hw = 1.f / 784.f;
        #pragma unroll
        for (int j = 0; j < 4; ++j) {
            const int cg = (isl4 ? 0 : C4) + cl + j;    // global concat channel
            float* afp = af_out + ((size_t)b * C_TOTAL + cg) * L_TOT;
            float gp = 0.f;
            #pragma unroll
            for (int l = 0; l < L_TOT; ++l) {
                float v = acc[j][l] * inv_hw;
                afp[l] = v;
                if (l < 8) gp = fmaf(modulation[cg * L_TOT + l], v, gp);
            }
            g_out[(size_t)b * C_TOTAL + cg] = gp * 0.125f;
        }
    }
}

// ------------- K4: class_scores = g (16x3072) @ W_class^T (3072x2000) -------------------------------
__global__ __launch_bounds__(256) void class_kernel(
    const float* __restrict__ Wc, const float* __restrict__ g,
    float* __restrict__ out)
{
    const int wv   = threadIdx.x >> 6;
    const int lane = threadIdx.x & 63;
    const int k    = blockIdx.x * 4 + wv;

    const float4* w4p = (const float4*)(Wc + (size_t)k * C_TOTAL);
    float acc[NB];
    #pragma unroll
    for (int b = 0; b < NB; ++b) acc[b] = 0.f;

    for (int i = 0; i < C_TOTAL / 256; ++i) {
        const int c4i = i * 64 + lane;
        float4 w4 = w4p[c4i];
        #pragma unroll
        for (int b = 0; b < NB; ++b) {
            float4 g4 = ((const float4*)(g + (size_t)b * C_TOTAL))[c4i];
            acc[b] = fmaf(w4.x, g4.x, acc[b]);
            acc[b] = fmaf(w4.y, g4.y, acc[b]);
            acc[b] = fmaf(w4.z, g4.z, acc[b]);
            acc[b] = fmaf(w4.w, g4.w, acc[b]);
        }
    }
    #pragma unroll
    for (int b = 0; b < NB; ++b) {
        #pragma unroll
        for (int off = 32; off; off >>= 1) acc[b] += __shfl_down(acc[b], off, 64);
    }
    if (lane == 0) {
        #pragma unroll
        for (int b = 0; b < NB; ++b) out[(size_t)b * NK + k] = acc[b];
    }
}

extern "C" void kernel_launch(void* const* d_in, const int* in_sizes, int n_in,
                              void* d_out, int out_size, void* d_ws, size_t ws_size,
                              hipStream_t stream) {
    const float* l3  = (const float*)d_in[0];  // (16,1024,28,28)
    const float* l4  = (const float*)d_in[1];  // (16,2048,14,14)
    const float* Wl  = (const float*)d_in[2];  // (9,3072)
    const float* Wc  = (const float*)d_in[3];  // (2000,3072)
    const float* mod = (const float*)d_in[4];  // (1,3072,9)

    float* out  = (float*)d_out;
    float* cls  = out;             // 16*2000  = 32000
    float* maps = out + 32000;     // 16*9*784 = 112896
    float* af   = out + 144896;    // 16*3072*9 = 442368

    float* absum  = (float*)d_ws;                       // 16*9*784 = 112896 floats
    float* ab4sum = absum + NB * L_TOT * HW;            // 16*9*196 = 28224 floats
    float* asqp   = ab4sum + NB * L_TOT * HW4;          // 16 floats (9 used)
    float* mdown  = asqp + 16;                          // 16*9*196 = 28224 floats
    float* g      = mdown + NB * L_TOT * HW4;           // 16*3072 floats

    hipMemsetAsync(absum, 0, (size_t)(NB * L_TOT * HW + NB * L_TOT * HW4) * sizeof(float), stream);

    abx_kernel     <<<dim3(33, NB), 256, 0, stream>>>(l3, l4, Wl, ab4sum, absum, asqp);
    maps_fin_kernel<<<dim3(4, NB), 256, 0, stream>>>(absum, ab4sum, asqp, maps);
    mapsdown_kernel<<<NB, 256, 0, stream>>>(maps, mdown);
    pool_kernel    <<<dim3(48, NB), 256, 0, stream>>>(l3, l4, maps, mdown, mod, af, g);
    class_kernel   <<<NK / 4, 256, 0, stream>>>(Wc, g, cls);
}

// Round 7
// 180.082 us; speedup vs baseline: 1.1751x; 1.1751x over previous
//
#include <hip/hip_runtime.h>
#include <math.h>

// Problem constants
#define C_TOTAL 3072
#define C4 2048      // channels from l4 (upsampled half of concat: channels [0,2048))
#define C3 1024      // channels from l3 (channels [2048,3072))
#define HW  784      // 28*28
#define W_  28
#define HW4 196      // 14*14
#define W4  14
#define L_TOT 9      // landmarks + 1
#define NB  16       // batch
#define NK  2000     // classes
#define CH4 32       // l4 channel chunks (64 ch each)
#define CH3 32       // l3 channel chunks (32 ch each)
#define N3SUM (NB * L_TOT * HW)    // 112896
#define N4SUM (NB * L_TOT * HW4)   // 28224

// Bilinear upsample 14->28, align_corners=False (jax.image.resize semantics):
// src = 0.5*o - 0.25; even o=2j: taps (j-1, j) w (0.25, 0.75); odd o=2j+1: taps (j, j+1) w (0.75, 0.25); clamp.
__device__ __forceinline__ void up_taps(int o, int& i0, int& i1, float& w0, float& w1) {
    int j = o >> 1;
    if (o & 1) { i0 = j;                       i1 = (j + 1 < W4) ? j + 1 : W4 - 1; w0 = 0.75f; w1 = 0.25f; }
    else       { i0 = (j - 1 > 0) ? j - 1 : 0; i1 = j;                             w0 = 0.25f; w1 = 0.75f; }
}

// weight that source index s contributes to output index o (adjoint of the upsample)
__device__ __forceinline__ float wdown(int o, int s) {
    int i0, i1; float w0, w1;
    up_taps(o, i0, i1, w0, w1);
    return (i0 == s ? w0 : 0.f) + (i1 == s ? w1 : 0.f);
}

// ------------- K1: fused front section — block-specialized on blockIdx.x ----------------------------
// x in [0,32):    ab4 partials ab4p[(x*NB+b)][l][q], 64-ch chunks      (q on 14x14 grid)
// x in [32,64):   ab3 partials ab3p[((x-32)*NB+b)][l][p], 32-ch chunks (p on 28x28 grid, float4)
// x == 64, b==0:  asq[l] = sum_c Wl[l][c]^2
// Grid (65,16) = 1040 blocks ≈ 4/CU for latency hiding. Plain coalesced partial writes (no atomics:
// device-scope atomics cross the non-coherent per-XCD L2s and cost ~20 µs at this volume — R6 lesson).
__global__ __launch_bounds__(256) void abx_kernel(
    const float* __restrict__ l3, const float* __restrict__ l4,
    const float* __restrict__ Wl,
    float* __restrict__ ab4p, float* __restrict__ ab3p, float* __restrict__ asqp)
{
    const int bx = blockIdx.x;
    const int b  = blockIdx.y;
    const int tid = threadIdx.x;

    if (bx < CH4) {
        // ---- ab4 section ----
        const int q = tid;
        if (q >= HW4) return;
        const float* l4b = l4 + (size_t)b * C4 * HW4;
        float acc[L_TOT];
        #pragma unroll
        for (int l = 0; l < L_TOT; ++l) acc[l] = 0.f;
        const int c0 = bx * (C4 / CH4);
        #pragma unroll 8
        for (int i = 0; i < C4 / CH4; ++i) {
            const int c = c0 + i;                       // wave-uniform -> scalar weight loads
            float xv = l4b[(size_t)c * HW4 + q];        // coalesced over q
            const float* wc = Wl + c;
            #pragma unroll
            for (int l = 0; l < L_TOT; ++l) acc[l] = fmaf(wc[l * C_TOTAL], xv, acc[l]);
        }
        float* outp = ab4p + (size_t)(bx * NB + b) * (L_TOT * HW4) + q;
        #pragma unroll
        for (int l = 0; l < L_TOT; ++l) outp[l * HW4] = acc[l];
    } else if (bx < CH4 + CH3) {
        // ---- ab3 section ----
        const int t = tid;                  // float4 pixel group 0..195
        const int j = bx - CH4;             // channel chunk
        if (t >= HW / 4) return;
        const float4* l3b = (const float4*)(l3 + (size_t)b * C3 * HW);
        float4 acc[L_TOT];
        #pragma unroll
        for (int l = 0; l < L_TOT; ++l) acc[l] = make_float4(0.f, 0.f, 0.f, 0.f);
        const int c0 = j * (C3 / CH3);
        #pragma unroll 8
        for (int i = 0; i < C3 / CH3; ++i) {
            const int c = c0 + i;                               // wave-uniform
            float4 xv = l3b[(size_t)c * (HW / 4) + t];          // 1 KB per wave instr
            const float* wc = Wl + C4 + c;
            #pragma unroll
            for (int l = 0; l < L_TOT; ++l) {
                const float w = wc[l * C_TOTAL];                // scalar load
                acc[l].x = fmaf(w, xv.x, acc[l].x);
                acc[l].y = fmaf(w, xv.y, acc[l].y);
                acc[l].z = fmaf(w, xv.z, acc[l].z);
                acc[l].w = fmaf(w, xv.w, acc[l].w);
            }
        }
        float4* outp = (float4*)(ab3p + (size_t)(j * NB + b) * (L_TOT * HW));
        #pragma unroll
        for (int l = 0; l < L_TOT; ++l) outp[l * (HW / 4) + t] = acc[l];
    } else {
        // ---- asq section (one block total) ----
        if (b != 0) return;
        __shared__ float red[4];
        for (int l = 0; l < L_TOT; ++l) {
            const float* wrow = Wl + (size_t)l * C_TOTAL;
            float s0 = 0.f, s1 = 0.f, s2 = 0.f, s3 = 0.f;
            {
                float a = wrow[tid +  0 * 256];
                float bb = wrow[tid + 1 * 256];
                float c = wrow[tid +  2 * 256];
                float d = wrow[tid +  3 * 256];
                float e = wrow[tid +  4 * 256];
                float f = wrow[tid +  5 * 256];
                float gg = wrow[tid + 6 * 256];
                float h = wrow[tid +  7 * 256];
                float i2 = wrow[tid + 8 * 256];
                float j2 = wrow[tid + 9 * 256];
                float k2 = wrow[tid + 10 * 256];
                float m2 = wrow[tid + 11 * 256];
                s0 = fmaf(a, a, fmaf(e, e, i2 * i2));
                s1 = fmaf(bb, bb, fmaf(f, f, j2 * j2));
                s2 = fmaf(c, c, fmaf(gg, gg, k2 * k2));
                s3 = fmaf(d, d, fmaf(h, h, m2 * m2));
            }
            float s = (s0 + s1) + (s2 + s3);
            #pragma unroll
            for (int off = 32; off; off >>= 1) s += __shfl_down(s, off, 64);
            const int w = tid >> 6, lane = tid & 63;
            if (lane == 0) red[w] = s;
            __syncthreads();
            if (tid == 0) asqp[l] = (red[0] + red[1]) + (red[2] + red[3]);
            __syncthreads();
        }
    }
}

// ------------- K1r: wide partial reduction — absum = sum_j ab3p, ab4sum = sum_j ab4p ----------------
// Grid-stride-free: 552 blocks x 256 threads cover 141120 outputs; 32 independent loads/thread.
__global__ __launch_bounds__(256) void reduce_kernel(
    const float* __restrict__ ab3p, const float* __restrict__ ab4p,
    float* __restrict__ absum, float* __restrict__ ab4sum)
{
    const int i = blockIdx.x * 256 + threadIdx.x;
    if (i < N3SUM) {
        const int b = i / (L_TOT * HW), r = i - b * (L_TOT * HW);
        float s = 0.f;
        #pragma unroll
        for (int j = 0; j < CH3; ++j) s += ab3p[(size_t)(j * NB + b) * (L_TOT * HW) + r];
        absum[i] = s;
    } else {
        const int i2 = i - N3SUM;
        if (i2 < N4SUM) {
            const int b = i2 / (L_TOT * HW4), r = i2 - b * (L_TOT * HW4);
            float s = 0.f;
            #pragma unroll
            for (int j = 0; j < CH4; ++j) s += ab4p[(size_t)(j * NB + b) * (L_TOT * HW4) + r];
            ab4sum[i2] = s;
        }
    }
}

// ------------- K2: finalize — absum + upsample(ab4sum) + softmax -> maps; + maps_down ---------------
// One block per b (1024 threads). maps kept in LDS for the fused downsample-adjoint pass.
__global__ __launch_bounds__(1024) void maps_fin_kernel(
    const float* __restrict__ absum, const float* __restrict__ ab4sum,
    const float* __restrict__ asqp, float* __restrict__ maps_out,
    float* __restrict__ mdown)
{
    __shared__ float msh[L_TOT * HW];     // 28224 B
    __shared__ float ab4s[L_TOT * HW4];   // 7056 B
    __shared__ float asq_s[L_TOT];

    const int tid = threadIdx.x;
    const int b   = blockIdx.x;

    for (int v = tid; v < L_TOT * HW4; v += 1024)
        ab4s[v] = ab4sum[(size_t)b * (L_TOT * HW4) + v];
    if (tid < L_TOT) asq_s[tid] = asqp[tid];
    __syncthreads();

    const int p = tid;
    if (p < HW) {
        const int y = p / W_, x = p % W_;
        int y0, y1, x0, x1; float wy0, wy1, wx0, wx1;
        up_taps(y, y0, y1, wy0, wy1);
        up_taps(x, x0, x1, wx0, wx1);

        const float* ap = absum + (size_t)b * (L_TOT * HW) + p;
        float lg[L_TOT];
        #pragma unroll
        for (int l = 0; l < L_TOT; ++l) {
            float s = ap[l * HW];                                   // coalesced over p
            const float* a = ab4s + l * HW4;
            float t0 = fmaf(a[y0 * W4 + x1], wx1, a[y0 * W4 + x0] * wx0);
            float t1 = fmaf(a[y1 * W4 + x1], wx1, a[y1 * W4 + x0] * wx0);
            float up = fmaf(t1, wy1, t0 * wy0);
            lg[l] = 2.f * (s + up) - asq_s[l];
        }
        float m = lg[0];
        #pragma unroll
        for (int l = 1; l < L_TOT; ++l) m = fmaxf(m, lg[l]);
        float sum = 0.f;
        #pragma unroll
        for (int l = 0; l < L_TOT; ++l) { lg[l] = __expf(lg[l] - m); sum += lg[l]; }
        const float inv = 1.f / sum;
        float* mp = maps_out + (size_t)b * L_TOT * HW + p;
        #pragma unroll
        for (int l = 0; l < L_TOT; ++l) {
            const float v = lg[l] * inv;
            mp[l * HW] = v;
            msh[l * HW + p] = v;
        }
    }
    __syncthreads();

    // fused maps_down from LDS maps
    for (int v = tid; v < L_TOT * HW4; v += 1024) {
        const int l = v / HW4, q = v % HW4;
        const int sy = q / W4, sx = q % W4;
        float s = 0.f;
        int oy0 = 2 * sy - 1; if (oy0 < 0) oy0 = 0;
        int oy1 = 2 * sy + 2; if (oy1 > 27) oy1 = 27;
        int ox0 = 2 * sx - 1; if (ox0 < 0) ox0 = 0;
        int ox1 = 2 * sx + 2; if (ox1 > 27) ox1 = 27;
        for (int oy = oy0; oy <= oy1; ++oy) {
            const float wy = wdown(oy, sy);
            const float* row = msh + l * HW + oy * W_;
            for (int ox = ox0; ox <= ox1; ++ox)
                s = fmaf(wy * wdown(ox, sx), row[ox], s);
        }
        mdown[(size_t)b * (L_TOT * HW4) + v] = s;
    }
}

// ------------- K3: pooling -> all_features + g ------------------------------------------------------
// Block 256 = 4 waves x (4 ch-subgroups x 16 px-lanes); each lane owns 4 consecutive channels.
// l4 blocks (cblk<32): float4-load precomputed maps_down (7KB); read l4 directly (no upsample).
// l3 blocks: stage maps[9][784] into LDS. Block owns full pixel range -> no atomics.
__global__ __launch_bounds__(256) void pool_kernel(
    const float* __restrict__ l3, const float* __restrict__ l4,
    const float* __restrict__ maps, const float* __restrict__ mdown,
    const float* __restrict__ modulation,
    float* __restrict__ af_out, float* __restrict__ g_out)
{
    __shared__ float msh[L_TOT * HW];   // 28224 B; l4 blocks use first 9*196

    const int tid  = threadIdx.x;
    const int b    = blockIdx.y;
    const int cblk = blockIdx.x;        // 0..47
    const bool isl4 = (cblk < 32);

    if (isl4) {
        const float4* src = (const float4*)(mdown + (size_t)b * (L_TOT * HW4));
        for (int v = tid; v < (L_TOT * HW4) / 4; v += 256)   // 441 float4s
            ((float4*)msh)[v] = src[v];
    } else {
        const float4* src = (const float4*)(maps + (size_t)b * L_TOT * HW);
        for (int v = tid; v < (L_TOT * HW) / 4; v += 256)
            ((float4*)msh)[v] = src[v];
    }
    __syncthreads();

    const int   PMAX  = isl4 ? HW4 : HW;
    const float* xbase = isl4 ? (l4 + (size_t)b * C4 * HW4)
                              : (l3 + (size_t)b * C3 * HW);
    const int cloc0 = (isl4 ? cblk : (cblk - 32)) * 64;
    const int w = tid >> 6, s = (tid >> 4) & 3, t = tid & 15;
    const int cl = cloc0 + w * 16 + s * 4;      // local channel base of this lane's 4 channels

    float acc[4][L_TOT];
    #pragma unroll
    for (int j = 0; j < 4; ++j)
        #pragma unroll
        for (int l = 0; l < L_TOT; ++l) acc[j][l] = 0.f;

    const int kmax = isl4 ? 4 : 13;
    for (int k = 0; k < kmax; ++k) {
        const int p = (t << 2) + (k << 6);
        if (p < PMAX) {
            float4 m4[L_TOT];
            #pragma unroll
            for (int l = 0; l < L_TOT; ++l) m4[l] = *(const float4*)&msh[l * PMAX + p];
            #pragma unroll
            for (int j = 0; j < 4; ++j) {
                float4 x4 = *(const float4*)&xbase[(size_t)(cl + j) * PMAX + p];
                #pragma unroll
                for (int l = 0; l < L_TOT; ++l)
                    acc[j][l] = fmaf(x4.x, m4[l].x, fmaf(x4.y, m4[l].y,
                                fmaf(x4.z, m4[l].z, fmaf(x4.w, m4[l].w, acc[j][l]))));
            }
        }
    }

    // reduce across the 16 pixel-lanes of each subgroup
    #pragma unroll
    for (int j = 0; j < 4; ++j)
        #pragma unroll
        for (int l = 0; l < L_TOT; ++l) {
            float v = acc[j][l];
            v += __shfl_xor(v, 1, 16);
            v += __shfl_xor(v, 2, 16);
            v += __shfl_xor(v, 4, 16);
            v += __shfl_xor(v, 8, 16);
            acc[j][l] = v;
        }

    if (t == 0) {
        const float inv_hw = 1.f / 784.f;
        #pragma unroll
        for (int j = 0; j < 4; ++j) {
            const int cg = (isl4 ? 0 : C4) + cl + j;    // global concat channel
            float* afp = af_out + ((size_t)b * C_TOTAL + cg) * L_TOT;
            float gp = 0.f;
            #pragma unroll
            for (int l = 0; l < L_TOT; ++l) {
                float v = acc[j][l] * inv_hw;
                afp[l] = v;
                if (l < 8) gp = fmaf(modulation[cg * L_TOT + l], v, gp);
            }
            g_out[(size_t)b * C_TOTAL + cg] = gp * 0.125f;
        }
    }
}

// ------------- K4: class_scores = g (16x3072) @ W_class^T (3072x2000) -------------------------------
__global__ __launch_bounds__(256) void class_kernel(
    const float* __restrict__ Wc, const float* __restrict__ g,
    float* __restrict__ out)
{
    const int wv   = threadIdx.x >> 6;
    const int lane = threadIdx.x & 63;
    const int k    = blockIdx.x * 4 + wv;

    const float4* w4p = (const float4*)(Wc + (size_t)k * C_TOTAL);
    float acc[NB];
    #pragma unroll
    for (int b = 0; b < NB; ++b) acc[b] = 0.f;

    for (int i = 0; i < C_TOTAL / 256; ++i) {
        const int c4i = i * 64 + lane;
        float4 w4 = w4p[c4i];
        #pragma unroll
        for (int b = 0; b < NB; ++b) {
            float4 g4 = ((const float4*)(g + (size_t)b * C_TOTAL))[c4i];
            acc[b] = fmaf(w4.x, g4.x, acc[b]);
            acc[b] = fmaf(w4.y, g4.y, acc[b]);
            acc[b] = fmaf(w4.z, g4.z, acc[b]);
            acc[b] = fmaf(w4.w, g4.w, acc[b]);
        }
    }
    #pragma unroll
    for (int b = 0; b < NB; ++b) {
        #pragma unroll
        for (int off = 32; off; off >>= 1) acc[b] += __shfl_down(acc[b], off, 64);
    }
    if (lane == 0) {
        #pragma unroll
        for (int b = 0; b < NB; ++b) out[(size_t)b * NK + k] = acc[b];
    }
}

extern "C" void kernel_launch(void* const* d_in, const int* in_sizes, int n_in,
                              void* d_out, int out_size, void* d_ws, size_t ws_size,
                              hipStream_t stream) {
    const float* l3  = (const float*)d_in[0];  // (16,1024,28,28)
    const float* l4  = (const float*)d_in[1];  // (16,2048,14,14)
    const float* Wl  = (const float*)d_in[2];  // (9,3072)
    const float* Wc  = (const float*)d_in[3];  // (2000,3072)
    const float* mod = (const float*)d_in[4];  // (1,3072,9)

    float* out  = (float*)d_out;
    float* cls  = out;             // 16*2000  = 32000
    float* maps = out + 32000;     // 16*9*784 = 112896
    float* af   = out + 144896;    // 16*3072*9 = 442368

    float* ab4p   = (float*)d_ws;                          // CH4*16*9*196  =  903168 floats
    float* ab3p   = ab4p + (size_t)CH4 * NB * L_TOT * HW4; // CH3*16*9*784  = 3612672 floats
    float* absum  = ab3p + (size_t)CH3 * NB * L_TOT * HW;  // 112896 floats
    float* ab4sum = absum + N3SUM;                         // 28224 floats
    float* asqp   = ab4sum + N4SUM;                        // 16 floats (9 used)
    float* mdown  = asqp + 16;                             // 28224 floats
    float* g      = mdown + N4SUM;                         // 49152 floats

    abx_kernel     <<<dim3(CH4 + CH3 + 1, NB), 256, 0, stream>>>(l3, l4, Wl, ab4p, ab3p, asqp);
    reduce_kernel  <<<(N3SUM + N4SUM + 255) / 256, 256, 0, stream>>>(ab3p, ab4p, absum, ab4sum);
    maps_fin_kernel<<<NB, 1024, 0, stream>>>(absum, ab4sum, asqp, maps, mdown);
    pool_kernel    <<<dim3(48, NB), 256, 0, stream>>>(l3, l4, maps, mdown, mod, af, g);
    class_kernel   <<<NK / 4, 256, 0, stream>>>(Wc, g, cls);
}

// Round 9
// 178.710 us; speedup vs baseline: 1.1841x; 1.0077x over previous
//
#include <hip/hip_runtime.h>
#include <math.h>

// Problem constants
#define C_TOTAL 3072
#define C4 2048      // channels from l4 (upsampled half of concat: channels [0,2048))
#define C3 1024      // channels from l3 (channels [2048,3072))
#define HW  784      // 28*28
#define W_  28
#define HW4 196      // 14*14
#define W4  14
#define L_TOT 9      // landmarks + 1
#define NB  16       // batch
#define NK  2000     // classes
#define CH4 32       // l4 channel chunks (64 ch each)
#define CH3 32       // l3 channel chunks (32 ch each)
#define N3SUM (NB * L_TOT * HW)    // 112896
#define N4SUM (NB * L_TOT * HW4)   // 28224

// Bilinear upsample 14->28, align_corners=False (jax.image.resize semantics):
// src = 0.5*o - 0.25; even o=2j: taps (j-1, j) w (0.25, 0.75); odd o=2j+1: taps (j, j+1) w (0.75, 0.25); clamp.
__device__ __forceinline__ void up_taps(int o, int& i0, int& i1, float& w0, float& w1) {
    int j = o >> 1;
    if (o & 1) { i0 = j;                       i1 = (j + 1 < W4) ? j + 1 : W4 - 1; w0 = 0.75f; w1 = 0.25f; }
    else       { i0 = (j - 1 > 0) ? j - 1 : 0; i1 = j;                             w0 = 0.25f; w1 = 0.75f; }
}

// weight that source index s contributes to output index o (adjoint of the upsample)
__device__ __forceinline__ float wdown(int o, int s) {
    int i0, i1; float w0, w1;
    up_taps(o, i0, i1, w0, w1);
    return (i0 == s ? w0 : 0.f) + (i1 == s ? w1 : 0.f);
}

// ------------- K1: fused front section — block-specialized on blockIdx.x ----------------------------
// x in [0,32):    ab4 partials ab4p[(x*NB+b)][l][q], 64-ch chunks (float4 loads, 4-stream LDS reduce)
// x in [32,64):   ab3 partials ab3p[((x-32)*NB+b)][l][p], 32-ch chunks (float4 pixel loads)
// x == 64, b==0:  asq[l] = sum_c Wl[l][c]^2
// Grid (65,16) = 1040 blocks ≈ 4/CU. Plain coalesced partial writes (no atomics: device-scope
// atomics cross the non-coherent per-XCD L2s — R6 cost ~20 µs at this volume).
__global__ __launch_bounds__(256) void abx_kernel(
    const float* __restrict__ l3, const float* __restrict__ l4,
    const float* __restrict__ Wl,
    float* __restrict__ ab4p, float* __restrict__ ab3p, float* __restrict__ asqp)
{
    __shared__ float4 red[4][L_TOT][49];   // 28224 B; only the ab4 branch uses it

    const int bx = blockIdx.x;
    const int b  = blockIdx.y;
    const int tid = threadIdx.x;

    if (bx < CH4) {
        // ---- ab4 section: 4 channel-streams x 49 float4 pixel-groups ----
        const int s = tid >> 6;         // stream 0..3 (16 channels each)
        const int g = tid & 63;         // float4 pixel group; active g < 49
        const int c0 = bx * 64;         // chunk base channel
        float4 acc[L_TOT];
        #pragma unroll
        for (int l = 0; l < L_TOT; ++l) acc[l] = make_float4(0.f, 0.f, 0.f, 0.f);
        if (g < 49) {
            // 64-ch slab is contiguous: 64*196 floats = 3136 float4; channel row = 49 float4s
            const float4* slab = (const float4*)(l4 + ((size_t)b * C4 + c0) * HW4);
            #pragma unroll 8
            for (int i = 0; i < 16; ++i) {
                const int c = s * 16 + i;                    // local channel (wave-uniform)
                float4 xv = slab[c * 49 + g];                // 784B contiguous per (s,i)
                const float* wc = Wl + c0 + c;
                #pragma unroll
                for (int l = 0; l < L_TOT; ++l) {
                    const float w = wc[l * C_TOTAL];         // scalar load
                    acc[l].x = fmaf(w, xv.x, acc[l].x);
                    acc[l].y = fmaf(w, xv.y, acc[l].y);
                    acc[l].z = fmaf(w, xv.z, acc[l].z);
                    acc[l].w = fmaf(w, xv.w, acc[l].w);
                }
            }
            #pragma unroll
            for (int l = 0; l < L_TOT; ++l) red[s][l][g] = acc[l];  // lanes stride-1: conflict-free
        }
        __syncthreads();
        // 441 outputs > 256 threads: MUST stride (R8 bug: `if (tid < 441)` left 185 unwritten)
        for (int v = tid; v < L_TOT * 49; v += 256) {
            const int l = v / 49, g2 = v % 49;
            float4 r0 = red[0][l][g2], r1 = red[1][l][g2];
            float4 r2 = red[2][l][g2], r3 = red[3][l][g2];
            float4 r = make_float4((r0.x + r1.x) + (r2.x + r3.x),
                                   (r0.y + r1.y) + (r2.y + r3.y),
                                   (r0.z + r1.z) + (r2.z + r3.z),
                                   (r0.w + r1.w) + (r2.w + r3.w));
            float4* out4 = (float4*)(ab4p + (size_t)(bx * NB + b) * (L_TOT * HW4));
            out4[v] = r;                                      // coalesced float4 writes
        }
    } else if (bx < CH4 + CH3) {
        // ---- ab3 section ----
        const int t = tid;                  // float4 pixel group 0..195
        const int j = bx - CH4;             // channel chunk
        if (t >= HW / 4) return;
        const float4* l3b = (const float4*)(l3 + (size_t)b * C3 * HW);
        float4 acc[L_TOT];
        #pragma unroll
        for (int l = 0; l < L_TOT; ++l) acc[l] = make_float4(0.f, 0.f, 0.f, 0.f);
        const int c0 = j * (C3 / CH3);
        #pragma unroll 8
        for (int i = 0; i < C3 / CH3; ++i) {
            const int c = c0 + i;                               // wave-uniform
            float4 xv = l3b[(size_t)c * (HW / 4) + t];          // 1 KB per wave instr
            const float* wc = Wl + C4 + c;
            #pragma unroll
            for (int l = 0; l < L_TOT; ++l) {
                const float w = wc[l * C_TOTAL];                // scalar load
                acc[l].x = fmaf(w, xv.x, acc[l].x);
                acc[l].y = fmaf(w, xv.y, acc[l].y);
                acc[l].z = fmaf(w, xv.z, acc[l].z);
                acc[l].w = fmaf(w, xv.w, acc[l].w);
            }
        }
        float4* outp = (float4*)(ab3p + (size_t)(j * NB + b) * (L_TOT * HW));
        #pragma unroll
        for (int l = 0; l < L_TOT; ++l) outp[l * (HW / 4) + t] = acc[l];
    } else {
        // ---- asq section (one block total) ----
        if (b != 0) return;
        __shared__ float redx[4];
        for (int l = 0; l < L_TOT; ++l) {
            const float* wrow = Wl + (size_t)l * C_TOTAL;
            float s0 = 0.f, s1 = 0.f, s2 = 0.f, s3 = 0.f;
            {
                float a = wrow[tid +  0 * 256];
                float bb = wrow[tid + 1 * 256];
                float c = wrow[tid +  2 * 256];
                float d = wrow[tid +  3 * 256];
                float e = wrow[tid +  4 * 256];
                float f = wrow[tid +  5 * 256];
                float gg = wrow[tid + 6 * 256];
                float h = wrow[tid +  7 * 256];
                float i2 = wrow[tid + 8 * 256];
                float j2 = wrow[tid + 9 * 256];
                float k2 = wrow[tid + 10 * 256];
                float m2 = wrow[tid + 11 * 256];
                s0 = fmaf(a, a, fmaf(e, e, i2 * i2));
                s1 = fmaf(bb, bb, fmaf(f, f, j2 * j2));
                s2 = fmaf(c, c, fmaf(gg, gg, k2 * k2));
                s3 = fmaf(d, d, fmaf(h, h, m2 * m2));
            }
            float s = (s0 + s1) + (s2 + s3);
            #pragma unroll
            for (int off = 32; off; off >>= 1) s += __shfl_down(s, off, 64);
            const int w = tid >> 6, lane = tid & 63;
            if (lane == 0) redx[w] = s;
            __syncthreads();
            if (tid == 0) asqp[l] = (redx[0] + redx[1]) + (redx[2] + redx[3]);
            __syncthreads();
        }
    }
}

// ------------- K1r: wide partial reduction (float4) — absum = sum_j ab3p, ab4sum = sum_j ab4p -------
// 138 blocks x 256 threads cover 35280 float4 outputs; 32 independent 1KB wave-loads per thread.
__global__ __launch_bounds__(256) void reduce_kernel(
    const float* __restrict__ ab3p, const float* __restrict__ ab4p,
    float* __restrict__ absum, float* __restrict__ ab4sum)
{
    const int i4 = blockIdx.x * 256 + threadIdx.x;
    const int n3 = N3SUM / 4;              // 28224 float4s
    if (i4 < n3) {
        const int b = i4 / (L_TOT * HW / 4), r = i4 - b * (L_TOT * HW / 4);
        const float4* src = (const float4*)ab3p;
        float4 s = make_float4(0.f, 0.f, 0.f, 0.f);
        #pragma unroll
        for (int j = 0; j < CH3; ++j) {
            float4 v = src[(size_t)(j * NB + b) * (L_TOT * HW / 4) + r];
            s.x += v.x; s.y += v.y; s.z += v.z; s.w += v.w;
        }
        ((float4*)absum)[i4] = s;
    } else {
        const int i2 = i4 - n3;
        if (i2 < N4SUM / 4) {
            const int b = i2 / (L_TOT * HW4 / 4), r = i2 - b * (L_TOT * HW4 / 4);
            const float4* src = (const float4*)ab4p;
            float4 s = make_float4(0.f, 0.f, 0.f, 0.f);
            #pragma unroll
            for (int j = 0; j < CH4; ++j) {
                float4 v = src[(size_t)(j * NB + b) * (L_TOT * HW4 / 4) + r];
                s.x += v.x; s.y += v.y; s.z += v.z; s.w += v.w;
            }
            ((float4*)ab4sum)[i2] = s;
        }
    }
}

// ------------- K2: finalize — absum + upsample(ab4sum) + softmax -> maps; + maps_down ---------------
// One block per b (1024 threads). maps kept in LDS for the fused downsample-adjoint pass.
__global__ __launch_bounds__(1024) void maps_fin_kernel(
    const float* __restrict__ absum, const float* __restrict__ ab4sum,
    const float* __restrict__ asqp, float* __restrict__ maps_out,
    float* __restrict__ mdown)
{
    __shared__ float msh[L_TOT * HW];     // 28224 B
    __shared__ float ab4s[L_TOT * HW4];   // 7056 B
    __shared__ float asq_s[L_TOT];

    const int tid = threadIdx.x;
    const int b   = blockIdx.x;

    for (int v = tid; v < L_TOT * HW4; v += 1024)
        ab4s[v] = ab4sum[(size_t)b * (L_TOT * HW4) + v];
    if (tid < L_TOT) asq_s[tid] = asqp[tid];
    __syncthreads();

    const int p = tid;
    if (p < HW) {
        const int y = p / W_, x = p % W_;
        int y0, y1, x0, x1; float wy0, wy1, wx0, wx1;
        up_taps(y, y0, y1, wy0, wy1);
        up_taps(x, x0, x1, wx0, wx1);

        const float* ap = absum + (size_t)b * (L_TOT * HW) + p;
        float lg[L_TOT];
        #pragma unroll
        for (int l = 0; l < L_TOT; ++l) {
            float s = ap[l * HW];                                   // coalesced over p
            const float* a = ab4s + l * HW4;
            float t0 = fmaf(a[y0 * W4 + x1], wx1, a[y0 * W4 + x0] * wx0);
            float t1 = fmaf(a[y1 * W4 + x1], wx1, a[y1 * W4 + x0] * wx0);
            float up = fmaf(t1, wy1, t0 * wy0);
            lg[l] = 2.f * (s + up) - asq_s[l];
        }
        float m = lg[0];
        #pragma unroll
        for (int l = 1; l < L_TOT; ++l) m = fmaxf(m, lg[l]);
        float sum = 0.f;
        #pragma unroll
        for (int l = 0; l < L_TOT; ++l) { lg[l] = __expf(lg[l] - m); sum += lg[l]; }
        const float inv = 1.f / sum;
        float* mp = maps_out + (size_t)b * L_TOT * HW + p;
        #pragma unroll
        for (int l = 0; l < L_TOT; ++l) {
            const float v = lg[l] * inv;
            mp[l * HW] = v;
            msh[l * HW + p] = v;
        }
    }
    __syncthreads();

    // fused maps_down from LDS maps
    for (int v = tid; v < L_TOT * HW4; v += 1024) {
        const int l = v / HW4, q = v % HW4;
        const int sy = q / W4, sx = q % W4;
        float s = 0.f;
        int oy0 = 2 * sy - 1; if (oy0 < 0) oy0 = 0;
        int oy1 = 2 * sy + 2; if (oy1 > 27) oy1 = 27;
        int ox0 = 2 * sx - 1; if (ox0 < 0) ox0 = 0;
        int ox1 = 2 * sx + 2; if (ox1 > 27) ox1 = 27;
        for (int oy = oy0; oy <= oy1; ++oy) {
            const float wy = wdown(oy, sy);
            const float* row = msh + l * HW + oy * W_;
            for (int ox = ox0; ox <= ox1; ++ox)
                s = fmaf(wy * wdown(ox, sx), row[ox], s);
        }
        mdown[(size_t)b * (L_TOT * HW4) + v] = s;
    }
}

// ------------- K3: pooling -> all_features + g ------------------------------------------------------
// Block 256 = 4 waves x (4 ch-subgroups x 16 px-lanes); each lane owns 4 consecutive channels.
// l4 blocks (cblk<32): float4-load precomputed maps_down (7KB); read l4 directly (no upsample).
// l3 blocks: stage maps[9][784] into LDS. Block owns full pixel range -> no atomics.
__global__ __launch_bounds__(256) void pool_kernel(
    const float* __restrict__ l3, const float* __restrict__ l4,
    const float* __restrict__ maps, const float* __restrict__ mdown,
    const float* __restrict__ modulation,
    float* __restrict__ af_out, float* __restrict__ g_out)
{
    __shared__ float msh[L_TOT * HW];   // 28224 B; l4 blocks use first 9*196

    const int tid  = threadIdx.x;
    const int b    = blockIdx.y;
    const int cblk = blockIdx.x;        // 0..47
    const bool isl4 = (cblk < 32);

    if (isl4) {
        const float4* src = (const float4*)(mdown + (size_t)b * (L_TOT * HW4));
        for (int v = tid; v < (L_TOT * HW4) / 4; v += 256)   // 441 float4s
            ((float4*)msh)[v] = src[v];
    } else {
        const float4* src = (const float4*)(maps + (size_t)b * L_TOT * HW);
        for (int v = tid; v < (L_TOT * HW) / 4; v += 256)
            ((float4*)msh)[v] = src[v];
    }
    __syncthreads();

    const int   PMAX  = isl4 ? HW4 : HW;
    const float* xbase = isl4 ? (l4 + (size_t)b * C4 * HW4)
                              : (l3 + (size_t)b * C3 * HW);
    const int cloc0 = (isl4 ? cblk : (cblk - 32)) * 64;
    const int w = tid >> 6, s = (tid >> 4) & 3, t = tid & 15;
    const int cl = cloc0 + w * 16 + s * 4;      // local channel base of this lane's 4 channels

    float acc[4][L_TOT];
    #pragma unroll
    for (int j = 0; j < 4; ++j)
        #pragma unroll
        for (int l = 0; l < L_TOT; ++l) acc[j][l] = 0.f;

    const int kmax = isl4 ? 4 : 13;
    for (int k = 0; k < kmax; ++k) {
        const int p = (t << 2) + (k << 6);
        if (p < PMAX) {
            float4 m4[L_TOT];
            #pragma unroll
            for (int l = 0; l < L_TOT; ++l) m4[l] = *(const float4*)&msh[l * PMAX + p];
            #pragma unroll
            for (int j = 0; j < 4; ++j) {
                float4 x4 = *(const float4*)&xbase[(size_t)(cl + j) * PMAX + p];
                #pragma unroll
                for (int l = 0; l < L_TOT; ++l)
                    acc[j][l] = fmaf(x4.x, m4[l].x, fmaf(x4.y, m4[l].y,
                                fmaf(x4.z, m4[l].z, fmaf(x4.w, m4[l].w, acc[j][l]))));
            }
        }
    }

    // reduce across the 16 pixel-lanes of each subgroup
    #pragma unroll
    for (int j = 0; j < 4; ++j)
        #pragma unroll
        for (int l = 0; l < L_TOT; ++l) {
            float v = acc[j][l];
            v += __shfl_xor(v, 1, 16);
            v += __shfl_xor(v, 2, 16);
            v += __shfl_xor(v, 4, 16);
            v += __shfl_xor(v, 8, 16);
            acc[j][l] = v;
        }

    if (t == 0) {
        const float inv_hw = 1.f / 784.f;
        #pragma unroll
        for (int j = 0; j < 4; ++j) {
            const int cg = (isl4 ? 0 : C4) + cl + j;    // global concat channel
            float* afp = af_out + ((size_t)b * C_TOTAL + cg) * L_TOT;
            float gp = 0.f;
            #pragma unroll
            for (int l = 0; l < L_TOT; ++l) {
                float v = acc[j][l] * inv_hw;
                afp[l] = v;
                if (l < 8) gp = fmaf(modulation[cg * L_TOT + l], v, gp);
            }
            g_out[(size_t)b * C_TOTAL + cg] = gp * 0.125f;
        }
    }
}

// ------------- K4: class_scores = g (16x3072) @ W_class^T (3072x2000) -------------------------------
__global__ __launch_bounds__(256) void class_kernel(
    const float* __restrict__ Wc, const float* __restrict__ g,
    float* __restrict__ out)
{
    const int wv   = threadIdx.x >> 6;
    const int lane = threadIdx.x & 63;
    const int k    = blockIdx.x * 4 + wv;

    const float4* w4p = (const float4*)(Wc + (size_t)k * C_TOTAL);
    float acc[NB];
    #pragma unroll
    for (int b = 0; b < NB; ++b) acc[b] = 0.f;

    for (int i = 0; i < C_TOTAL / 256; ++i) {
        const int c4i = i * 64 + lane;
        float4 w4 = w4p[c4i];
        #pragma unroll
        for (int b = 0; b < NB; ++b) {
            float4 g4 = ((const float4*)(g + (size_t)b * C_TOTAL))[c4i];
            acc[b] = fmaf(w4.x, g4.x, acc[b]);
            acc[b] = fmaf(w4.y, g4.y, acc[b]);
            acc[b] = fmaf(w4.z, g4.z, acc[b]);
            acc[b] = fmaf(w4.w, g4.w, acc[b]);
        }
    }
    #pragma unroll
    for (int b = 0; b < NB; ++b) {
        #pragma unroll
        for (int off = 32; off; off >>= 1) acc[b] += __shfl_down(acc[b], off, 64);
    }
    if (lane == 0) {
        #pragma unroll
        for (int b = 0; b < NB; ++b) out[(size_t)b * NK + k] = acc[b];
    }
}

extern "C" void kernel_launch(void* const* d_in, const int* in_sizes, int n_in,
                              void* d_out, int out_size, void* d_ws, size_t ws_size,
                              hipStream_t stream) {
    const float* l3  = (const float*)d_in[0];  // (16,1024,28,28)
    const float* l4  = (const float*)d_in[1];  // (16,2048,14,14)
    const float* Wl  = (const float*)d_in[2];  // (9,3072)
    const float* Wc  = (const float*)d_in[3];  // (2000,3072)
    const float* mod = (const float*)d_in[4];  // (1,3072,9)

    float* out  = (float*)d_out;
    float* cls  = out;             // 16*2000  = 32000
    float* maps = out + 32000;     // 16*9*784 = 112896
    float* af   = out + 144896;    // 16*3072*9 = 442368

    float* ab4p   = (float*)d_ws;                          // CH4*16*9*196  =  903168 floats
    float* ab3p   = ab4p + (size_t)CH4 * NB * L_TOT * HW4; // CH3*16*9*784  = 3612672 floats
    float* absum  = ab3p + (size_t)CH3 * NB * L_TOT * HW;  // 112896 floats
    float* ab4sum = absum + N3SUM;                         // 28224 floats
    float* asqp   = ab4sum + N4SUM;                        // 16 floats (9 used)
    float* mdown  = asqp + 16;                             // 28224 floats
    float* g      = mdown + N4SUM;                         // 49152 floats

    abx_kernel     <<<dim3(CH4 + CH3 + 1, NB), 256, 0, stream>>>(l3, l4, Wl, ab4p, ab3p, asqp);
    reduce_kernel  <<<((N3SUM + N4SUM) / 4 + 255) / 256, 256, 0, stream>>>(ab3p, ab4p, absum, ab4sum);
    maps_fin_kernel<<<NB, 1024, 0, stream>>>(absum, ab4sum, asqp, maps, mdown);
    pool_kernel    <<<dim3(48, NB), 256, 0, stream>>>(l3, l4, maps, mdown, mod, af, g);
    class_kernel   <<<NK / 4, 256, 0, stream>>>(Wc, g, cls);
}